// Round 11
// baseline (318.791 us; speedup 1.0000x reference)
//
#include <hip/hip_runtime.h>
#include <hip/hip_bf16.h>
#include <cstddef>

typedef __hip_bfloat16 bf16;
typedef unsigned short u16;
typedef __attribute__((ext_vector_type(8))) short short8;
typedef __attribute__((ext_vector_type(4))) float float4v;
typedef __attribute__((ext_vector_type(2))) float float2v;

#define HD 256
#define A_MAX 128

static __device__ __forceinline__ float b2f(const bf16 v) { return __bfloat162float(v); }
static __device__ __forceinline__ bf16 f2b(float v) { return __float2bfloat16(v); }

static __device__ __forceinline__ float2v up2(unsigned int u) {
  union { unsigned int i; float f; } a, b;
  a.i = u << 16; b.i = u & 0xffff0000u;
  float2v r; r.x = a.f; r.y = b.f; return r;
}

static __device__ __forceinline__ float ldf(const void* p, size_t i, bool f32) {
  return f32 ? ((const float*)p)[i] : b2f(((const bf16*)p)[i]);
}
template <bool F32>
static __device__ __forceinline__ float ldt(const void* p, size_t i) {
  return F32 ? ((const float*)p)[i] : b2f(((const bf16*)p)[i]);
}
static __device__ __forceinline__ void stf(void* p, size_t i, bool f32, float v) {
  if (f32) ((float*)p)[i] = v;
  else     ((bf16*)p)[i] = f2b(v);
}

__global__ void k_sentinel(float* out, int n, float v) {
  int i = blockIdx.x * blockDim.x + threadIdx.x;
  if (i < n) out[i] = v;
}

// ---------------- init: dtype probe + deg zeroing ----------------
__global__ void k_init(const u16* __restrict__ xbits, int* __restrict__ flag,
                       int* deg, int N) {
  int i = blockIdx.x * blockDim.x + threadIdx.x;
  if (blockIdx.x == 0 && threadIdx.x < 64) {
    int l = threadIdx.x;
    int huge = 0;
    for (int k = l; k < 256; k += 64) {
      u16 u = xbits[2 * k];
      int ex = (u >> 7) & 0xFF;
      if (ex >= 0xB0) huge++;
    }
#pragma unroll
    for (int off = 32; off > 0; off >>= 1) huge += __shfl_xor(huge, off, 64);
    if (l == 0) *flag = (huge >= 20) ? 1 : 0;
  }
  if (i < N) deg[i] = 0;
}

__global__ void k_hist(const int* __restrict__ dst, int* __restrict__ deg, int E) {
  int e = blockIdx.x * blockDim.x + threadIdx.x;
  if (e < E) atomicAdd(&deg[dst[e]], 1);
}

// single-block wave-shuffle exclusive scan (verified rounds 5-6)
__global__ void k_scan(const int* __restrict__ deg, int* __restrict__ offs, int n) {
  __shared__ int wsum[17];
  __shared__ int carry_s;
  int t = threadIdx.x, w = t >> 6, l = t & 63;
  if (t == 0) carry_s = 0;
  __syncthreads();
  for (int base = 0; base < n; base += 1024) {
    int i = base + t;
    int v = (i < n) ? deg[i] : 0;
    int x = v;
#pragma unroll
    for (int off = 1; off < 64; off <<= 1) {
      int y = __shfl_up(x, off, 64);
      if (l >= off) x += y;
    }
    if (l == 63) wsum[w] = x;
    __syncthreads();
    if (t == 0) {
      int s = 0;
#pragma unroll
      for (int k = 0; k < 16; k++) { int tmp = wsum[k]; wsum[k] = s; s += tmp; }
      wsum[16] = s;
    }
    __syncthreads();
    int c = carry_s;
    if (i < n) offs[i] = c + wsum[w] + x - v;   // exclusive
    __syncthreads();
    if (t == 0) carry_s = c + wsum[16];
    __syncthreads();
  }
  if (t == 0) offs[n] = carry_s;
}

// ---------------- fused independent stage: scatter | xform1 | prepw ----------------
// blocks [0, nSc): CSR scatter (offs-shift trick: afterwards offs[d] = segment end)
// blocks [nSc, nSc+nX1): layer-1 transform, 4 nodes/block
// blocks [nSc+nX1, nSc+nX1+256): Wfrag MFMA-fragment packing (+bias in first)
__global__ void k_misc(const int* __restrict__ src, const int* __restrict__ dst,
                       const void* __restrict__ ea, int* __restrict__ offs,
                       int2* __restrict__ csr,
                       const void* __restrict__ x,
                       const void* __restrict__ Wl1, const void* __restrict__ bl1,
                       const void* __restrict__ Wr1, const void* __restrict__ br1,
                       bf16* __restrict__ P, bf16* __restrict__ Q,
                       const void* __restrict__ Wl2, const void* __restrict__ Wr2,
                       const void* __restrict__ bl2, const void* __restrict__ br2,
                       bf16* __restrict__ Wfrag, bf16* __restrict__ bias2,
                       const int* __restrict__ flag,
                       int E, int N, int nSc, int nX1) {
  bool f32 = flag[0] != 0;
  int b = blockIdx.x, t = threadIdx.x;
  if (b < nSc) {
    int e = b * 256 + t;
    if (e >= E) return;
    int d = dst[e];
    int pos = atomicAdd(&offs[d], 1);
    int2 v;
    v.x = src[e];
    v.y = __float_as_int(ldf(ea, e, f32));
    csr[pos] = v;
  } else if (b < nSc + nX1) {
    int n0 = (b - nSc) * 4;
    float wl0 = ldf(Wl1, t, f32),          wl1 = ldf(Wl1, HD + t, f32);
    float wl2 = ldf(Wl1, 2 * HD + t, f32), wl3 = ldf(Wl1, 3 * HD + t, f32);
    float wr0 = ldf(Wr1, t, f32),          wr1 = ldf(Wr1, HD + t, f32);
    float wr2 = ldf(Wr1, 2 * HD + t, f32), wr3 = ldf(Wr1, 3 * HD + t, f32);
    float bbl = ldf(bl1, t, f32), bbr = ldf(br1, t, f32);
#pragma unroll
    for (int k = 0; k < 4; k++) {
      int n = n0 + k;
      if (n >= N) break;
      float x0 = ldf(x, (size_t)n * 4 + 0, f32), x1 = ldf(x, (size_t)n * 4 + 1, f32);
      float x2 = ldf(x, (size_t)n * 4 + 2, f32), x3 = ldf(x, (size_t)n * 4 + 3, f32);
      P[(size_t)n * HD + t] = f2b(bbl + x0 * wl0 + x1 * wl1 + x2 * wl2 + x3 * wl3);
      Q[(size_t)n * HD + t] = f2b(bbr + x0 * wr0 + x1 * wr1 + x2 * wr2 + x3 * wr3);
    }
  } else {
    int pb = b - nSc - nX1;       // [0,256): 32 ct x 8 kt
    int ct = pb >> 3, kt = pb & 7;
    if (pb == 0) {
      bias2[t]       = f2b(ldf(bl2, t, f32));
      bias2[t + 256] = f2b(ldf(br2, t, f32));
    }
#pragma unroll
    for (int half = 0; half < 2; half++) {
      int e = half * 256 + t;     // [0,512)
      int m = e & 15;
      int rest = e >> 4;
      int quad = rest >> 3, j = rest & 7;
      int l = quad * 16 + m;
      int k = kt * 32 + quad * 8 + j;
      int n = ct * 16 + m;
      const void* W = (n < 256) ? Wl2 : Wr2;
      float v = ldf(W, (size_t)k * 256 + (n & 255), f32);
      Wfrag[(size_t)pb * 512 + l * 8 + j] = f2b(v);
    }
  }
}

// ---- layer 2 as bf16 MFMA GEMM with fragment-packed B ----
__global__ __launch_bounds__(256) void k_xform2_mfma(
    const bf16* __restrict__ hin, const bf16* __restrict__ Wfrag,
    const bf16* __restrict__ bias2,
    bf16* __restrict__ P, bf16* __restrict__ Q, int N) {
  int w = threadIdx.x >> 6, l = threadIdx.x & 63;
  int r0 = blockIdx.x * 16;
  if (r0 >= N) return;
  int m = l & 15;
  int quad = l >> 4;
  int row = r0 + m;
  if (row >= N) row = N - 1;

  short8 a[8];
  const u16* arow = (const u16*)hin + (size_t)row * 256;
#pragma unroll
  for (int kt = 0; kt < 8; kt++)
    a[kt] = *(const short8*)(arow + kt * 32 + quad * 8);

#pragma unroll
  for (int ct = 0; ct < 8; ct++) {
    int c_tile = w * 8 + ct;
    int c = c_tile * 16 + m;
    const u16* bbase = (const u16*)Wfrag + ((size_t)c_tile * 8) * 512 + l * 8;
    float4v acc = {0.f, 0.f, 0.f, 0.f};
#pragma unroll
    for (int kt = 0; kt < 8; kt++) {
      short8 b = *(const short8*)(bbase + kt * 512);
      acc = __builtin_amdgcn_mfma_f32_16x16x32_bf16(a[kt], b, acc, 0, 0, 0);
    }
    float bv = b2f(bias2[c]);
#pragma unroll
    for (int i = 0; i < 4; i++) {
      int r = r0 + quad * 4 + i;
      if (r < N) {
        float v = acc[i] + bv;
        if (c < 256) P[(size_t)r * 256 + c] = f2b(v);
        else         Q[(size_t)r * 256 + (c - 256)] = f2b(v);
      }
    }
  }
}

// ---------------- GATv2: 1 wave per dst node, 4-way edge unroll ----------------
__global__ __launch_bounds__(256) void k_gat(
    const bf16* __restrict__ xl, const bf16* __restrict__ xr,
    const int2* __restrict__ csr, const int* __restrict__ offs,
    const void* __restrict__ We, const void* __restrict__ att,
    const void* __restrict__ bias,
    bf16* __restrict__ hout, const int* __restrict__ flag, int N) {
  int w = threadIdx.x >> 6, l = threadIdx.x & 63;
  int n = blockIdx.x * 4 + w;
  if (n >= N) return;
  bool f32 = flag[0] != 0;
  int d0 = l << 2;

  uint2 xu = *(const uint2*)((const u16*)xr + (size_t)n * HD + d0);
  float2v xr01 = up2(xu.x), xr23 = up2(xu.y);
  float2v We01, We23, at01, at23;
  We01.x = ldf(We, d0 + 0, f32); We01.y = ldf(We, d0 + 1, f32);
  We23.x = ldf(We, d0 + 2, f32); We23.y = ldf(We, d0 + 3, f32);
  at01.x = ldf(att, d0 + 0, f32); at01.y = ldf(att, d0 + 1, f32);
  at23.x = ldf(att, d0 + 2, f32); at23.y = ldf(att, d0 + 3, f32);

  int beg = (n > 0) ? offs[n - 1] : 0;
  int end = offs[n];
  float2v acc01 = {0.f, 0.f}, acc23 = {0.f, 0.f};
  float dn = 0.f;

  int j = beg;
  for (; j + 4 <= end; j += 4) {
    int2 v[4];
#pragma unroll
    for (int q = 0; q < 4; q++) v[q] = csr[j + q];
    uint2 su[4];
#pragma unroll
    for (int q = 0; q < 4; q++)
      su[q] = *(const uint2*)((const u16*)xl + (size_t)v[q].x * HD + d0);
    float2v x01[4], x23[4];
    float ps[4];
#pragma unroll
    for (int q = 0; q < 4; q++) {
      x01[q] = up2(su[q].x); x23[q] = up2(su[q].y);
      float eav = __int_as_float(v[q].y);
      float2v ev; ev.x = eav; ev.y = eav;
      float2v m01 = x01[q] + xr01 + ev * We01;
      float2v m23 = x23[q] + xr23 + ev * We23;
      float2v lr01, lr23;
      lr01.x = fmaxf(m01.x, 0.2f * m01.x); lr01.y = fmaxf(m01.y, 0.2f * m01.y);
      lr23.x = fmaxf(m23.x, 0.2f * m23.x); lr23.y = fmaxf(m23.y, 0.2f * m23.y);
      float2v pp = lr01 * at01 + lr23 * at23;
      ps[q] = pp.x + pp.y;
    }
#pragma unroll
    for (int off = 1; off <= 8; off <<= 1) {
#pragma unroll
      for (int q = 0; q < 4; q++) ps[q] += __shfl_xor(ps[q], off, 64);
    }
#pragma unroll
    for (int q = 0; q < 4; q++) {
      float a = __expf(fminf(fmaxf(ps[q], -40.f), 40.f));
      dn += a;
      float2v av; av.x = a; av.y = a;
      acc01 += av * x01[q];
      acc23 += av * x23[q];
    }
  }
  for (; j < end; j++) {
    int2 v = csr[j];
    float eav = __int_as_float(v.y);
    uint2 su = *(const uint2*)((const u16*)xl + (size_t)v.x * HD + d0);
    float2v x01 = up2(su.x), x23 = up2(su.y);
    float2v ev; ev.x = eav; ev.y = eav;
    float2v m01 = x01 + xr01 + ev * We01;
    float2v m23 = x23 + xr23 + ev * We23;
    float2v lr01, lr23;
    lr01.x = fmaxf(m01.x, 0.2f * m01.x); lr01.y = fmaxf(m01.y, 0.2f * m01.y);
    lr23.x = fmaxf(m23.x, 0.2f * m23.x); lr23.y = fmaxf(m23.y, 0.2f * m23.y);
    float2v pp = lr01 * at01 + lr23 * at23;
    float ps = pp.x + pp.y;
    ps += __shfl_xor(ps, 1, 64);
    ps += __shfl_xor(ps, 2, 64);
    ps += __shfl_xor(ps, 4, 64);
    ps += __shfl_xor(ps, 8, 64);
    float a = __expf(fminf(fmaxf(ps, -40.f), 40.f));
    dn += a;
    float2v av; av.x = a; av.y = a;
    acc01 += av * x01;
    acc23 += av * x23;
  }

  float inv = 1.f / (dn + 1e-16f);
  bf16 o[4];
  o[0] = f2b(fmaxf(acc01.x * inv + ldf(bias, d0 + 0, f32), 0.f));
  o[1] = f2b(fmaxf(acc01.y * inv + ldf(bias, d0 + 1, f32), 0.f));
  o[2] = f2b(fmaxf(acc23.x * inv + ldf(bias, d0 + 2, f32), 0.f));
  o[3] = f2b(fmaxf(acc23.y * inv + ldf(bias, d0 + 3, f32), 0.f));
  *(ushort4*)((u16*)hout + (size_t)n * HD + d0) = *(ushort4*)o;
}

// ---------------- heads with fused mean-pool ----------------

static __device__ __forceinline__ int lb(const int* a, int n, int v) {
  int lo = 0, hi = n;
  while (lo < hi) { int m = (lo + hi) >> 1; if (a[m] < v) lo = m + 1; else hi = m; }
  return lo;
}

template <bool F32>
static __device__ void mlp_body(const bf16* __restrict__ R,
                                const int* __restrict__ bidx, int N,
                                const int* __restrict__ act,
                                const void* Wa1, const void* ba1, const void* Wa2, const void* ba2,
                                const void* Wa3, const void* ba3,
                                const void* Wc1, const void* bc1, const void* Wc2, const void* bc2,
                                const void* Wc3, const void* bc3,
                                void* __restrict__ out, int B, int A) {
  __shared__ float f[HD];
  __shared__ float p1[2][128];
  __shared__ float h1[128];
  __shared__ float p2[4][64];
  __shared__ float h2[64];
  __shared__ float lg[A_MAX];
  __shared__ float sc[2];
  int blk = blockIdx.x, g = blk >> 1, which = blk & 1, t = threadIdx.x;  // 256 threads
  int s_ = lb(bidx, N, g), e_ = lb(bidx, N, g + 1);
  float inv = 1.f / fmaxf((float)(e_ - s_), 1.f);
  // fused mean-pool: sum this graph's rows, 4-way unrolled
  {
    float a0 = 0.f, a1 = 0.f, a2 = 0.f, a3 = 0.f;
    int i = s_;
    for (; i + 4 <= e_; i += 4) {
      a0 += b2f(R[(size_t)(i + 0) * HD + t]);
      a1 += b2f(R[(size_t)(i + 1) * HD + t]);
      a2 += b2f(R[(size_t)(i + 2) * HD + t]);
      a3 += b2f(R[(size_t)(i + 3) * HD + t]);
    }
    for (; i < e_; i++) a0 += b2f(R[(size_t)i * HD + t]);
    f[t] = ((a0 + a1) + (a2 + a3)) * inv;
  }
  __syncthreads();

  const void *W1 = which ? Wc1 : Wa1, *B1 = which ? bc1 : ba1;
  const void *W2 = which ? Wc2 : Wa2, *B2 = which ? bc2 : ba2;

  {
    int j = t & 127, half = t >> 7;
    int i0 = half * 128;
    float a0 = 0.f, a1 = 0.f, a2 = 0.f, a3 = 0.f;
    for (int u = 0; u < 128; u += 4) {
      a0 += f[i0 + u + 0] * ldt<F32>(W1, (size_t)(i0 + u + 0) * 128 + j);
      a1 += f[i0 + u + 1] * ldt<F32>(W1, (size_t)(i0 + u + 1) * 128 + j);
      a2 += f[i0 + u + 2] * ldt<F32>(W1, (size_t)(i0 + u + 2) * 128 + j);
      a3 += f[i0 + u + 3] * ldt<F32>(W1, (size_t)(i0 + u + 3) * 128 + j);
    }
    p1[half][j] = (a0 + a1) + (a2 + a3);
  }
  __syncthreads();
  if (t < 128) h1[t] = fmaxf(p1[0][t] + p1[1][t] + ldt<F32>(B1, t), 0.f);
  __syncthreads();

  {
    int j = t & 63, q = t >> 6;
    int i0 = q * 32;
    float a0 = 0.f, a1 = 0.f;
    for (int u = 0; u < 32; u += 2) {
      a0 += h1[i0 + u + 0] * ldt<F32>(W2, (size_t)(i0 + u + 0) * 64 + j);
      a1 += h1[i0 + u + 1] * ldt<F32>(W2, (size_t)(i0 + u + 1) * 64 + j);
    }
    p2[q][j] = a0 + a1;
  }
  __syncthreads();
  if (t < 64) h2[t] = fmaxf(p2[0][t] + p2[1][t] + p2[2][t] + p2[3][t] + ldt<F32>(B2, t), 0.f);
  __syncthreads();

  if (which == 0) {
    if (t < A) {
      float a0 = 0.f, a1 = 0.f, a2 = 0.f, a3 = 0.f;
      for (int i = 0; i < 64; i += 4) {
        a0 += h2[i + 0] * ldt<F32>(Wa3, (size_t)(i + 0) * A + t);
        a1 += h2[i + 1] * ldt<F32>(Wa3, (size_t)(i + 1) * A + t);
        a2 += h2[i + 2] * ldt<F32>(Wa3, (size_t)(i + 2) * A + t);
        a3 += h2[i + 3] * ldt<F32>(Wa3, (size_t)(i + 3) * A + t);
      }
      lg[t] = (a0 + a1) + (a2 + a3) + ldt<F32>(ba3, t);
    }
    __syncthreads();
    if (t == 0) {
      float mx = -3.4e38f;
      for (int i = 0; i < A; i++) mx = fmaxf(mx, lg[i]);
      float s = 0.f;
      for (int i = 0; i < A; i++) s += __expf(lg[i] - mx);
      sc[0] = mx;
      sc[1] = logf(s);
    }
    __syncthreads();
    float mx = sc[0], lse = sc[1];
    if (t < A) stf(out, (size_t)g * A + t, F32, lg[t]);
    if (t == 0) {
      int a = act[g];
      stf(out, (size_t)B * A + g, F32, lg[a] - mx - lse);
      float ent = 0.f;
      for (int i = 0; i < A; i++) {
        float l = lg[i] - mx - lse;
        ent -= __expf(l) * l;
      }
      stf(out, (size_t)B * A + B + g, F32, ent);
    }
  } else {
    if (t < 64) {
      float v = h2[t] * ldt<F32>(Wc3, t);
#pragma unroll
      for (int off = 32; off > 0; off >>= 1) v += __shfl_xor(v, off, 64);
      if (t == 0) stf(out, (size_t)B * A + 2 * B + g, F32, v + ldt<F32>(bc3, 0));
    }
  }
}

__global__ void k_mlp(const bf16* __restrict__ R,
                      const int* __restrict__ bidx, int N,
                      const int* __restrict__ act,
                      const void* Wa1, const void* ba1, const void* Wa2, const void* ba2,
                      const void* Wa3, const void* ba3,
                      const void* Wc1, const void* bc1, const void* Wc2, const void* bc2,
                      const void* Wc3, const void* bc3,
                      void* __restrict__ out, const int* __restrict__ flag, int B, int A) {
  if (flag[0] != 0)
    mlp_body<true >(R, bidx, N, act, Wa1, ba1, Wa2, ba2, Wa3, ba3,
                    Wc1, bc1, Wc2, bc2, Wc3, bc3, out, B, A);
  else
    mlp_body<false>(R, bidx, N, act, Wa1, ba1, Wa2, ba2, Wa3, ba3,
                    Wc1, bc1, Wc2, bc2, Wc3, bc3, out, B, A);
}

// ---------------- launch ----------------

extern "C" void kernel_launch(void* const* d_in, const int* in_sizes, int n_in,
                              void* d_out, int out_size, void* d_ws, size_t ws_size,
                              hipStream_t stream) {
  const void* x    = d_in[0];
  const int*  ei   = (const int*)d_in[1];
  const void* ea   = d_in[2];
  const int*  bidx = (const int*)d_in[3];
  const int*  act  = (const int*)d_in[4];
  const void *Wl1 = d_in[5],  *bl1 = d_in[6];
  const void *Wr1 = d_in[7],  *br1 = d_in[8];
  const void *We1 = d_in[9],  *att1 = d_in[10];
  const void *b1  = d_in[11];
  const void *Wl2 = d_in[12], *bl2 = d_in[13];
  const void *Wr2 = d_in[14], *br2 = d_in[15];
  const void *We2 = d_in[16], *att2 = d_in[17];
  const void *b2  = d_in[18];
  const void *Wc1 = d_in[19], *bc1 = d_in[20];
  const void *Wc2 = d_in[21], *bc2 = d_in[22];
  const void *Wc3 = d_in[23], *bc3 = d_in[24];
  const void *Wa1 = d_in[25], *ba1 = d_in[26];
  const void *Wa2 = d_in[27], *ba2 = d_in[28];
  const void *Wa3 = d_in[29], *ba3 = d_in[30];

  const int N = in_sizes[0] / 4;
  const int E = in_sizes[1] / 2;
  const int B = in_sizes[4];
  const int A = in_sizes[30];

  char* p = (char*)d_ws;
  auto carve = [&](size_t bytes) {
    void* r = (void*)p;
    p += (bytes + 255) & ~(size_t)255;
    return r;
  };
  int*   dflag   = (int*)carve(4);
  int*   deg     = (int*)carve((size_t)N * 4);
  int*   offs    = (int*)carve((size_t)(N + 1) * 4);
  int2*  csr     = (int2*)carve((size_t)E * 8);
  bf16*  P       = (bf16*)carve((size_t)N * HD * 2);
  bf16*  Q       = (bf16*)carve((size_t)N * HD * 2);
  bf16*  R       = (bf16*)carve((size_t)N * HD * 2);
  bf16*  Wfrag   = (bf16*)carve((size_t)512 * 256 * 2);
  bf16*  bias2   = (bf16*)carve((size_t)512 * 2);
  size_t need = (size_t)(p - (char*)d_ws);

  if (ws_size < need) {
    float v = 1000.f + (float)(ws_size >> 20);
    int n = out_size / 2;
    k_sentinel<<<(n + 255) / 256, 256, 0, stream>>>((float*)d_out, n, v);
    return;
  }

  const int* srcA = ei;
  const int* dstA = ei + E;

  int nSc = (E + 255) / 256;
  int nX1 = (N + 3) / 4;

  k_init<<<(N + 255) / 256, 256, 0, stream>>>((const u16*)x, dflag, deg, N);
  k_hist<<<(E + 255) / 256, 256, 0, stream>>>(dstA, deg, E);
  k_scan<<<1, 1024, 0, stream>>>(deg, offs, N);
  k_misc<<<nSc + nX1 + 256, 256, 0, stream>>>(srcA, dstA, ea, offs, csr,
                                              x, Wl1, bl1, Wr1, br1, P, Q,
                                              Wl2, Wr2, bl2, br2, Wfrag, bias2,
                                              dflag, E, N, nSc, nX1);
  k_gat<<<(N + 3) / 4, 256, 0, stream>>>(P, Q, csr, offs, We1, att1, b1, R, dflag, N);
  k_xform2_mfma<<<(N + 15) / 16, 256, 0, stream>>>(R, Wfrag, bias2, P, Q, N);
  k_gat<<<(N + 3) / 4, 256, 0, stream>>>(P, Q, csr, offs, We2, att2, b2, R, dflag, N);
  k_mlp<<<B * 2, 256, 0, stream>>>(R, bidx, N, act,
                                   Wa1, ba1, Wa2, ba2, Wa3, ba3,
                                   Wc1, bc1, Wc2, bc2, Wc3, bc3,
                                   d_out, dflag, B, A);
}

// Round 12
// 289.977 us; speedup vs baseline: 1.0994x; 1.0994x over previous
//
#include <hip/hip_runtime.h>
#include <hip/hip_bf16.h>
#include <cstddef>

typedef __hip_bfloat16 bf16;
typedef unsigned short u16;
typedef __attribute__((ext_vector_type(8))) short short8;
typedef __attribute__((ext_vector_type(4))) float float4v;
typedef __attribute__((ext_vector_type(2))) float float2v;

#define HD 256
#define A_MAX 128

static __device__ __forceinline__ float b2f(const bf16 v) { return __bfloat162float(v); }
static __device__ __forceinline__ bf16 f2b(float v) { return __float2bfloat16(v); }

static __device__ __forceinline__ float2v up2(unsigned int u) {
  union { unsigned int i; float f; } a, b;
  a.i = u << 16; b.i = u & 0xffff0000u;
  float2v r; r.x = a.f; r.y = b.f; return r;
}

static __device__ __forceinline__ float ldf(const void* p, size_t i, bool f32) {
  return f32 ? ((const float*)p)[i] : b2f(((const bf16*)p)[i]);
}
template <bool F32>
static __device__ __forceinline__ float ldt(const void* p, size_t i) {
  return F32 ? ((const float*)p)[i] : b2f(((const bf16*)p)[i]);
}
static __device__ __forceinline__ void stf(void* p, size_t i, bool f32, float v) {
  if (f32) ((float*)p)[i] = v;
  else     ((bf16*)p)[i] = f2b(v);
}

__global__ void k_sentinel(float* out, int n, float v) {
  int i = blockIdx.x * blockDim.x + threadIdx.x;
  if (i < n) out[i] = v;
}

// ---------------- init: dtype probe + deg zeroing ----------------
__global__ void k_init(const u16* __restrict__ xbits, int* __restrict__ flag,
                       int* deg, int N) {
  int i = blockIdx.x * blockDim.x + threadIdx.x;
  if (blockIdx.x == 0 && threadIdx.x < 64) {
    int l = threadIdx.x;
    int huge = 0;
    for (int k = l; k < 256; k += 64) {
      u16 u = xbits[2 * k];
      int ex = (u >> 7) & 0xFF;
      if (ex >= 0xB0) huge++;
    }
#pragma unroll
    for (int off = 32; off > 0; off >>= 1) huge += __shfl_xor(huge, off, 64);
    if (l == 0) *flag = (huge >= 20) ? 1 : 0;
  }
  if (i < N) deg[i] = 0;
}

__global__ void k_hist(const int* __restrict__ dst, int* __restrict__ deg, int E) {
  int e = blockIdx.x * blockDim.x + threadIdx.x;
  if (e < E) atomicAdd(&deg[dst[e]], 1);
}

// ---------------- 3-stage parallel scan (round-10 config) ----------------
__global__ void k_sumb(const int* __restrict__ deg, int* __restrict__ bsum, int n) {
  __shared__ int ws[16];
  int b = blockIdx.x, t = threadIdx.x;   // 1024 threads
  int i = b * 1024 + t;
  int v = (i < n) ? deg[i] : 0;
#pragma unroll
  for (int off = 32; off > 0; off >>= 1) v += __shfl_xor(v, off, 64);
  if ((t & 63) == 0) ws[t >> 6] = v;
  __syncthreads();
  if (t == 0) {
    int s = 0;
#pragma unroll
    for (int k = 0; k < 16; k++) s += ws[k];
    bsum[b] = s;
  }
}

__global__ void k_scanb(const int* __restrict__ bsum, int* __restrict__ boff,
                        int nb, int* __restrict__ offs, int n) {
  if (threadIdx.x == 0) {
    int s = 0;
    for (int i = 0; i < nb; i++) { boff[i] = s; s += bsum[i]; }
    offs[n] = s;
  }
}

__global__ void k_scanapply(const int* __restrict__ deg, const int* __restrict__ boff,
                            int* __restrict__ offs, int n) {
  __shared__ int wsum[16];
  int b = blockIdx.x, t = threadIdx.x, w = t >> 6, l = t & 63;  // 1024 threads
  int i = b * 1024 + t;
  int v = (i < n) ? deg[i] : 0;
  int x = v;
#pragma unroll
  for (int off = 1; off < 64; off <<= 1) {
    int y = __shfl_up(x, off, 64);
    if (l >= off) x += y;
  }
  if (l == 63) wsum[w] = x;
  __syncthreads();
  if (t == 0) {
    int s = 0;
#pragma unroll
    for (int k = 0; k < 16; k++) { int tmp = wsum[k]; wsum[k] = s; s += tmp; }
  }
  __syncthreads();
  if (i < n) offs[i] = boff[b] + wsum[w] + x - v;   // exclusive
}

// ---------------- fused independent stage: scatter | xform1 | prepw ----------------
// blocks [0, nSc): CSR scatter (offs-shift: afterwards offs[d] = segment end)
// blocks [nSc, nSc+nX1): layer-1 transform, 4 nodes/block
// blocks [nSc+nX1, nSc+nX1+256): Wfrag MFMA-fragment packing (+bias in first)
__global__ void k_misc(const int* __restrict__ src, const int* __restrict__ dst,
                       const void* __restrict__ ea, int* __restrict__ offs,
                       int2* __restrict__ csr,
                       const void* __restrict__ x,
                       const void* __restrict__ Wl1, const void* __restrict__ bl1,
                       const void* __restrict__ Wr1, const void* __restrict__ br1,
                       bf16* __restrict__ P, bf16* __restrict__ Q,
                       const void* __restrict__ Wl2, const void* __restrict__ Wr2,
                       const void* __restrict__ bl2, const void* __restrict__ br2,
                       bf16* __restrict__ Wfrag, bf16* __restrict__ bias2,
                       const int* __restrict__ flag,
                       int E, int N, int nSc, int nX1) {
  bool f32 = flag[0] != 0;
  int b = blockIdx.x, t = threadIdx.x;
  if (b < nSc) {
    int e = b * 256 + t;
    if (e >= E) return;
    int d = dst[e];
    int pos = atomicAdd(&offs[d], 1);
    int2 v;
    v.x = src[e];
    v.y = __float_as_int(ldf(ea, e, f32));
    csr[pos] = v;
  } else if (b < nSc + nX1) {
    int n0 = (b - nSc) * 4;
    float wl0 = ldf(Wl1, t, f32),          wl1 = ldf(Wl1, HD + t, f32);
    float wl2 = ldf(Wl1, 2 * HD + t, f32), wl3 = ldf(Wl1, 3 * HD + t, f32);
    float wr0 = ldf(Wr1, t, f32),          wr1 = ldf(Wr1, HD + t, f32);
    float wr2 = ldf(Wr1, 2 * HD + t, f32), wr3 = ldf(Wr1, 3 * HD + t, f32);
    float bbl = ldf(bl1, t, f32), bbr = ldf(br1, t, f32);
#pragma unroll
    for (int k = 0; k < 4; k++) {
      int n = n0 + k;
      if (n >= N) break;
      float x0 = ldf(x, (size_t)n * 4 + 0, f32), x1 = ldf(x, (size_t)n * 4 + 1, f32);
      float x2 = ldf(x, (size_t)n * 4 + 2, f32), x3 = ldf(x, (size_t)n * 4 + 3, f32);
      P[(size_t)n * HD + t] = f2b(bbl + x0 * wl0 + x1 * wl1 + x2 * wl2 + x3 * wl3);
      Q[(size_t)n * HD + t] = f2b(bbr + x0 * wr0 + x1 * wr1 + x2 * wr2 + x3 * wr3);
    }
  } else {
    int pb = b - nSc - nX1;       // [0,256): 32 ct x 8 kt
    int ct = pb >> 3, kt = pb & 7;
    if (pb == 0) {
      bias2[t]       = f2b(ldf(bl2, t, f32));
      bias2[t + 256] = f2b(ldf(br2, t, f32));
    }
#pragma unroll
    for (int half = 0; half < 2; half++) {
      int e = half * 256 + t;     // [0,512)
      int m = e & 15;
      int rest = e >> 4;
      int quad = rest >> 3, j = rest & 7;
      int l = quad * 16 + m;
      int k = kt * 32 + quad * 8 + j;
      int n = ct * 16 + m;
      const void* W = (n < 256) ? Wl2 : Wr2;
      float v = ldf(W, (size_t)k * 256 + (n & 255), f32);
      Wfrag[(size_t)pb * 512 + l * 8 + j] = f2b(v);
    }
  }
}

// ---- layer 2 as bf16 MFMA GEMM with fragment-packed B ----
__global__ __launch_bounds__(256) void k_xform2_mfma(
    const bf16* __restrict__ hin, const bf16* __restrict__ Wfrag,
    const bf16* __restrict__ bias2,
    bf16* __restrict__ P, bf16* __restrict__ Q, int N) {
  int w = threadIdx.x >> 6, l = threadIdx.x & 63;
  int r0 = blockIdx.x * 16;
  if (r0 >= N) return;
  int m = l & 15;
  int quad = l >> 4;
  int row = r0 + m;
  if (row >= N) row = N - 1;

  short8 a[8];
  const u16* arow = (const u16*)hin + (size_t)row * 256;
#pragma unroll
  for (int kt = 0; kt < 8; kt++)
    a[kt] = *(const short8*)(arow + kt * 32 + quad * 8);

#pragma unroll
  for (int ct = 0; ct < 8; ct++) {
    int c_tile = w * 8 + ct;
    int c = c_tile * 16 + m;
    const u16* bbase = (const u16*)Wfrag + ((size_t)c_tile * 8) * 512 + l * 8;
    float4v acc = {0.f, 0.f, 0.f, 0.f};
#pragma unroll
    for (int kt = 0; kt < 8; kt++) {
      short8 b = *(const short8*)(bbase + kt * 512);
      acc = __builtin_amdgcn_mfma_f32_16x16x32_bf16(a[kt], b, acc, 0, 0, 0);
    }
    float bv = b2f(bias2[c]);
#pragma unroll
    for (int i = 0; i < 4; i++) {
      int r = r0 + quad * 4 + i;
      if (r < N) {
        float v = acc[i] + bv;
        if (c < 256) P[(size_t)r * 256 + c] = f2b(v);
        else         Q[(size_t)r * 256 + (c - 256)] = f2b(v);
      }
    }
  }
}

// ---------------- GATv2: 1 wave per dst node, 4-way edge unroll ----------------
__global__ __launch_bounds__(256) void k_gat(
    const bf16* __restrict__ xl, const bf16* __restrict__ xr,
    const int2* __restrict__ csr, const int* __restrict__ offs,
    const void* __restrict__ We, const void* __restrict__ att,
    const void* __restrict__ bias,
    bf16* __restrict__ hout, const int* __restrict__ flag, int N) {
  int w = threadIdx.x >> 6, l = threadIdx.x & 63;
  int n = blockIdx.x * 4 + w;
  if (n >= N) return;
  bool f32 = flag[0] != 0;
  int d0 = l << 2;

  uint2 xu = *(const uint2*)((const u16*)xr + (size_t)n * HD + d0);
  float2v xr01 = up2(xu.x), xr23 = up2(xu.y);
  float2v We01, We23, at01, at23;
  We01.x = ldf(We, d0 + 0, f32); We01.y = ldf(We, d0 + 1, f32);
  We23.x = ldf(We, d0 + 2, f32); We23.y = ldf(We, d0 + 3, f32);
  at01.x = ldf(att, d0 + 0, f32); at01.y = ldf(att, d0 + 1, f32);
  at23.x = ldf(att, d0 + 2, f32); at23.y = ldf(att, d0 + 3, f32);

  int beg = (n > 0) ? offs[n - 1] : 0;
  int end = offs[n];
  float2v acc01 = {0.f, 0.f}, acc23 = {0.f, 0.f};
  float dn = 0.f;

  int j = beg;
  for (; j + 4 <= end; j += 4) {
    int2 v[4];
#pragma unroll
    for (int q = 0; q < 4; q++) v[q] = csr[j + q];
    uint2 su[4];
#pragma unroll
    for (int q = 0; q < 4; q++)
      su[q] = *(const uint2*)((const u16*)xl + (size_t)v[q].x * HD + d0);
    float2v x01[4], x23[4];
    float ps[4];
#pragma unroll
    for (int q = 0; q < 4; q++) {
      x01[q] = up2(su[q].x); x23[q] = up2(su[q].y);
      float eav = __int_as_float(v[q].y);
      float2v ev; ev.x = eav; ev.y = eav;
      float2v m01 = x01[q] + xr01 + ev * We01;
      float2v m23 = x23[q] + xr23 + ev * We23;
      float2v lr01, lr23;
      lr01.x = fmaxf(m01.x, 0.2f * m01.x); lr01.y = fmaxf(m01.y, 0.2f * m01.y);
      lr23.x = fmaxf(m23.x, 0.2f * m23.x); lr23.y = fmaxf(m23.y, 0.2f * m23.y);
      float2v pp = lr01 * at01 + lr23 * at23;
      ps[q] = pp.x + pp.y;
    }
#pragma unroll
    for (int off = 1; off <= 8; off <<= 1) {
#pragma unroll
      for (int q = 0; q < 4; q++) ps[q] += __shfl_xor(ps[q], off, 64);
    }
#pragma unroll
    for (int q = 0; q < 4; q++) {
      float a = __expf(fminf(fmaxf(ps[q], -40.f), 40.f));
      dn += a;
      float2v av; av.x = a; av.y = a;
      acc01 += av * x01[q];
      acc23 += av * x23[q];
    }
  }
  for (; j < end; j++) {
    int2 v = csr[j];
    float eav = __int_as_float(v.y);
    uint2 su = *(const uint2*)((const u16*)xl + (size_t)v.x * HD + d0);
    float2v x01 = up2(su.x), x23 = up2(su.y);
    float2v ev; ev.x = eav; ev.y = eav;
    float2v m01 = x01 + xr01 + ev * We01;
    float2v m23 = x23 + xr23 + ev * We23;
    float2v lr01, lr23;
    lr01.x = fmaxf(m01.x, 0.2f * m01.x); lr01.y = fmaxf(m01.y, 0.2f * m01.y);
    lr23.x = fmaxf(m23.x, 0.2f * m23.x); lr23.y = fmaxf(m23.y, 0.2f * m23.y);
    float2v pp = lr01 * at01 + lr23 * at23;
    float ps = pp.x + pp.y;
    ps += __shfl_xor(ps, 1, 64);
    ps += __shfl_xor(ps, 2, 64);
    ps += __shfl_xor(ps, 4, 64);
    ps += __shfl_xor(ps, 8, 64);
    float a = __expf(fminf(fmaxf(ps, -40.f), 40.f));
    dn += a;
    float2v av; av.x = a; av.y = a;
    acc01 += av * x01;
    acc23 += av * x23;
  }

  float inv = 1.f / (dn + 1e-16f);
  bf16 o[4];
  o[0] = f2b(fmaxf(acc01.x * inv + ldf(bias, d0 + 0, f32), 0.f));
  o[1] = f2b(fmaxf(acc01.y * inv + ldf(bias, d0 + 1, f32), 0.f));
  o[2] = f2b(fmaxf(acc23.x * inv + ldf(bias, d0 + 2, f32), 0.f));
  o[3] = f2b(fmaxf(acc23.y * inv + ldf(bias, d0 + 3, f32), 0.f));
  *(ushort4*)((u16*)hout + (size_t)n * HD + d0) = *(ushort4*)o;
}

// ---------------- pooling: atomic-free, 16 partial slabs, B*16 blocks ----------------

static __device__ __forceinline__ int lb(const int* a, int n, int v) {
  int lo = 0, hi = n;
  while (lo < hi) { int m = (lo + hi) >> 1; if (a[m] < v) lo = m + 1; else hi = m; }
  return lo;
}

__global__ void k_pool(const bf16* __restrict__ h, const int* __restrict__ bidx,
                       float* __restrict__ feats16, int Bc, int N) {
  int g = blockIdx.x >> 4, part = blockIdx.x & 15, t = threadIdx.x;
  int s = lb(bidx, N, g), e_ = lb(bidx, N, g + 1);
  float a0 = 0.f, a1 = 0.f, a2 = 0.f, a3 = 0.f;
  int i = s + part;
  for (; i + 48 < e_; i += 64) {
    a0 += b2f(h[(size_t)(i +  0) * HD + t]);
    a1 += b2f(h[(size_t)(i + 16) * HD + t]);
    a2 += b2f(h[(size_t)(i + 32) * HD + t]);
    a3 += b2f(h[(size_t)(i + 48) * HD + t]);
  }
  for (; i < e_; i += 16) a0 += b2f(h[(size_t)i * HD + t]);
  feats16[((size_t)part * Bc + g) * HD + t] = (a0 + a1) + (a2 + a3);
}

// ---------------- heads ----------------

template <bool F32>
static __device__ void mlp_body(const float* __restrict__ feats16,
                                const int* __restrict__ bidx, int N,
                                const int* __restrict__ act,
                                const void* Wa1, const void* ba1, const void* Wa2, const void* ba2,
                                const void* Wa3, const void* ba3,
                                const void* Wc1, const void* bc1, const void* Wc2, const void* bc2,
                                const void* Wc3, const void* bc3,
                                void* __restrict__ out, int B, int A) {
  __shared__ float f[HD];
  __shared__ float p1[2][128];
  __shared__ float h1[128];
  __shared__ float p2[4][64];
  __shared__ float h2[64];
  __shared__ float lg[A_MAX];
  __shared__ float sc[2];
  int blk = blockIdx.x, g = blk >> 1, which = blk & 1, t = threadIdx.x;  // 256 threads
  int s_ = lb(bidx, N, g), e_ = lb(bidx, N, g + 1);
  float inv = 1.f / fmaxf((float)(e_ - s_), 1.f);
  {
    float s0 = 0.f, s1 = 0.f, s2 = 0.f, s3 = 0.f;
#pragma unroll
    for (int pp = 0; pp < 16; pp += 4) {
      s0 += feats16[((size_t)(pp + 0) * B + g) * HD + t];
      s1 += feats16[((size_t)(pp + 1) * B + g) * HD + t];
      s2 += feats16[((size_t)(pp + 2) * B + g) * HD + t];
      s3 += feats16[((size_t)(pp + 3) * B + g) * HD + t];
    }
    f[t] = ((s0 + s1) + (s2 + s3)) * inv;
  }
  __syncthreads();

  const void *W1 = which ? Wc1 : Wa1, *B1 = which ? bc1 : ba1;
  const void *W2 = which ? Wc2 : Wa2, *B2 = which ? bc2 : ba2;

  {
    int j = t & 127, half = t >> 7;
    int i0 = half * 128;
    float a0 = 0.f, a1 = 0.f, a2 = 0.f, a3 = 0.f;
    for (int u = 0; u < 128; u += 4) {
      a0 += f[i0 + u + 0] * ldt<F32>(W1, (size_t)(i0 + u + 0) * 128 + j);
      a1 += f[i0 + u + 1] * ldt<F32>(W1, (size_t)(i0 + u + 1) * 128 + j);
      a2 += f[i0 + u + 2] * ldt<F32>(W1, (size_t)(i0 + u + 2) * 128 + j);
      a3 += f[i0 + u + 3] * ldt<F32>(W1, (size_t)(i0 + u + 3) * 128 + j);
    }
    p1[half][j] = (a0 + a1) + (a2 + a3);
  }
  __syncthreads();
  if (t < 128) h1[t] = fmaxf(p1[0][t] + p1[1][t] + ldt<F32>(B1, t), 0.f);
  __syncthreads();

  {
    int j = t & 63, q = t >> 6;
    int i0 = q * 32;
    float a0 = 0.f, a1 = 0.f;
    for (int u = 0; u < 32; u += 2) {
      a0 += h1[i0 + u + 0] * ldt<F32>(W2, (size_t)(i0 + u + 0) * 64 + j);
      a1 += h1[i0 + u + 1] * ldt<F32>(W2, (size_t)(i0 + u + 1) * 64 + j);
    }
    p2[q][j] = a0 + a1;
  }
  __syncthreads();
  if (t < 64) h2[t] = fmaxf(p2[0][t] + p2[1][t] + p2[2][t] + p2[3][t] + ldt<F32>(B2, t), 0.f);
  __syncthreads();

  if (which == 0) {
    if (t < A) {
      float a0 = 0.f, a1 = 0.f, a2 = 0.f, a3 = 0.f;
      for (int i = 0; i < 64; i += 4) {
        a0 += h2[i + 0] * ldt<F32>(Wa3, (size_t)(i + 0) * A + t);
        a1 += h2[i + 1] * ldt<F32>(Wa3, (size_t)(i + 1) * A + t);
        a2 += h2[i + 2] * ldt<F32>(Wa3, (size_t)(i + 2) * A + t);
        a3 += h2[i + 3] * ldt<F32>(Wa3, (size_t)(i + 3) * A + t);
      }
      lg[t] = (a0 + a1) + (a2 + a3) + ldt<F32>(ba3, t);
    }
    __syncthreads();
    if (t == 0) {
      float mx = -3.4e38f;
      for (int i = 0; i < A; i++) mx = fmaxf(mx, lg[i]);
      float s = 0.f;
      for (int i = 0; i < A; i++) s += __expf(lg[i] - mx);
      sc[0] = mx;
      sc[1] = logf(s);
    }
    __syncthreads();
    float mx = sc[0], lse = sc[1];
    if (t < A) stf(out, (size_t)g * A + t, F32, lg[t]);
    if (t == 0) {
      int a = act[g];
      stf(out, (size_t)B * A + g, F32, lg[a] - mx - lse);
      float ent = 0.f;
      for (int i = 0; i < A; i++) {
        float l = lg[i] - mx - lse;
        ent -= __expf(l) * l;
      }
      stf(out, (size_t)B * A + B + g, F32, ent);
    }
  } else {
    if (t < 64) {
      float v = h2[t] * ldt<F32>(Wc3, t);
#pragma unroll
      for (int off = 32; off > 0; off >>= 1) v += __shfl_xor(v, off, 64);
      if (t == 0) stf(out, (size_t)B * A + 2 * B + g, F32, v + ldt<F32>(bc3, 0));
    }
  }
}

__global__ void k_mlp(const float* __restrict__ feats16,
                      const int* __restrict__ bidx, int N,
                      const int* __restrict__ act,
                      const void* Wa1, const void* ba1, const void* Wa2, const void* ba2,
                      const void* Wa3, const void* ba3,
                      const void* Wc1, const void* bc1, const void* Wc2, const void* bc2,
                      const void* Wc3, const void* bc3,
                      void* __restrict__ out, const int* __restrict__ flag, int B, int A) {
  if (flag[0] != 0)
    mlp_body<true >(feats16, bidx, N, act, Wa1, ba1, Wa2, ba2, Wa3, ba3,
                    Wc1, bc1, Wc2, bc2, Wc3, bc3, out, B, A);
  else
    mlp_body<false>(feats16, bidx, N, act, Wa1, ba1, Wa2, ba2, Wa3, ba3,
                    Wc1, bc1, Wc2, bc2, Wc3, bc3, out, B, A);
}

// ---------------- launch ----------------

extern "C" void kernel_launch(void* const* d_in, const int* in_sizes, int n_in,
                              void* d_out, int out_size, void* d_ws, size_t ws_size,
                              hipStream_t stream) {
  const void* x    = d_in[0];
  const int*  ei   = (const int*)d_in[1];
  const void* ea   = d_in[2];
  const int*  bidx = (const int*)d_in[3];
  const int*  act  = (const int*)d_in[4];
  const void *Wl1 = d_in[5],  *bl1 = d_in[6];
  const void *Wr1 = d_in[7],  *br1 = d_in[8];
  const void *We1 = d_in[9],  *att1 = d_in[10];
  const void *b1  = d_in[11];
  const void *Wl2 = d_in[12], *bl2 = d_in[13];
  const void *Wr2 = d_in[14], *br2 = d_in[15];
  const void *We2 = d_in[16], *att2 = d_in[17];
  const void *b2  = d_in[18];
  const void *Wc1 = d_in[19], *bc1 = d_in[20];
  const void *Wc2 = d_in[21], *bc2 = d_in[22];
  const void *Wc3 = d_in[23], *bc3 = d_in[24];
  const void *Wa1 = d_in[25], *ba1 = d_in[26];
  const void *Wa2 = d_in[27], *ba2 = d_in[28];
  const void *Wa3 = d_in[29], *ba3 = d_in[30];

  const int N = in_sizes[0] / 4;
  const int E = in_sizes[1] / 2;
  const int B = in_sizes[4];
  const int A = in_sizes[30];

  char* p = (char*)d_ws;
  auto carve = [&](size_t bytes) {
    void* r = (void*)p;
    p += (bytes + 255) & ~(size_t)255;
    return r;
  };
  int*   dflag   = (int*)carve(4);
  int*   deg     = (int*)carve((size_t)N * 4);
  int*   offs    = (int*)carve((size_t)(N + 1) * 4);
  int2*  csr     = (int2*)carve((size_t)E * 8);
  bf16*  P       = (bf16*)carve((size_t)N * HD * 2);
  bf16*  Q       = (bf16*)carve((size_t)N * HD * 2);
  bf16*  R       = (bf16*)carve((size_t)N * HD * 2);
  bf16*  Wfrag   = (bf16*)carve((size_t)512 * 256 * 2);
  bf16*  bias2   = (bf16*)carve((size_t)512 * 2);
  float* feats16 = (float*)carve((size_t)16 * B * HD * 4);
  int    nb      = (N + 1023) / 1024;
  int*   bsum    = (int*)carve((size_t)nb * 4);
  int*   boff    = (int*)carve((size_t)nb * 4);
  size_t need = (size_t)(p - (char*)d_ws);

  if (ws_size < need) {
    float v = 1000.f + (float)(ws_size >> 20);
    int n = out_size / 2;
    k_sentinel<<<(n + 255) / 256, 256, 0, stream>>>((float*)d_out, n, v);
    return;
  }

  const int* srcA = ei;
  const int* dstA = ei + E;

  int nSc = (E + 255) / 256;
  int nX1 = (N + 3) / 4;

  k_init<<<(N + 255) / 256, 256, 0, stream>>>((const u16*)x, dflag, deg, N);
  k_hist<<<(E + 255) / 256, 256, 0, stream>>>(dstA, deg, E);
  k_sumb<<<nb, 1024, 0, stream>>>(deg, bsum, N);
  k_scanb<<<1, 64, 0, stream>>>(bsum, boff, nb, offs, N);
  k_scanapply<<<nb, 1024, 0, stream>>>(deg, boff, offs, N);
  k_misc<<<nSc + nX1 + 256, 256, 0, stream>>>(srcA, dstA, ea, offs, csr,
                                              x, Wl1, bl1, Wr1, br1, P, Q,
                                              Wl2, Wr2, bl2, br2, Wfrag, bias2,
                                              dflag, E, N, nSc, nX1);
  k_gat<<<(N + 3) / 4, 256, 0, stream>>>(P, Q, csr, offs, We1, att1, b1, R, dflag, N);
  k_xform2_mfma<<<(N + 15) / 16, 256, 0, stream>>>(R, Wfrag, bias2, P, Q, N);
  k_gat<<<(N + 3) / 4, 256, 0, stream>>>(P, Q, csr, offs, We2, att2, b2, R, dflag, N);
  k_pool<<<B * 16, 256, 0, stream>>>(R, bidx, feats16, B, N);
  k_mlp<<<B * 2, 256, 0, stream>>>(feats16, bidx, N, act,
                                   Wa1, ba1, Wa2, ba2, Wa3, ba3,
                                   Wc1, bc1, Wc2, bc2, Wc3, bc3,
                                   d_out, dflag, B, A);
}